// Round 15
// baseline (214.911 us; speedup 1.0000x reference)
//
#include <hip/hip_runtime.h>

#define EG   16000   // graph edges
#define NG   1000    // graph_size (block rows/cols)
#define BB   32      // batch
#define SIZE 16000   // feature length (NG*16)
#define CAP  64      // per-bin capacity (Poisson(16): P(>64) ~ 1e-18)

typedef float f32x4 __attribute__((ext_vector_type(4)));

// ---- kernel 1: gather strided edge headers into dense pk[e]=(t0<<10)|t1 ----
// Writes every entry each launch: ws poison is never read. No memset needed.
__global__ __launch_bounds__(256) void pack_kernel(
    const int* __restrict__ rows, const int* __restrict__ cols,
    int* __restrict__ pk)
{
    int e = blockIdx.x * 256 + threadIdx.x;
    if (e < EG) {
        int t0 = rows[(long)e << 8] >> 4;   // rows[e*256] = t0*16
        int t1 = cols[(long)e << 8] >> 4;   // cols[e*256] = t1*16
        pk[e] = (t0 << 10) | t1;            // 20 bits
    }
}

// ---- kernel 2: barrier-free balanced depth-2 spmm (direct w) ----
// One block per bin. Shared scan of dense pk -> sl[] (1 barrier). Then wave w
// free-runs edges w, w+4, w+8,... of the SHARED list (perfect +-1 balance;
// same edge->wave assignment & sum order as r10 -> identical numerics).
// Depth-2 register staging (sets A/B, statically named -- no runtime-indexed
// arrays, r12's spill lesson): edge k's 5 global loads issue 2 iterations
// early, so the reg-dependency waitcnt is a counted vmcnt, not a drain; no
// __syncthreads in the main loop (own-wave LDS only; lgkmcnt orders it).
// NOTE (r8/r9): no in-kernel grid barriers. NOTE (r3): stores line-clustered,
// wave-private. NOTE (r12): never partition the scan per-wave; never use
// runtime-indexed register arrays.
__global__ __launch_bounds__(256, 4) void spmm_kernel(
    const float* __restrict__ wm, const float* __restrict__ wlv,
    const float* __restrict__ ew, const float* __restrict__ x,
    const float* __restrict__ bm, const float* __restrict__ blv,
    const float* __restrict__ eb, const int* __restrict__ pk,
    float* __restrict__ out)
{
    __shared__ f32x4 vt[4][2][64];    // [wave][buf][i*4+jg] sampled weights (8KB)
    __shared__ f32x4 xs[4][2][160];   // [wave][buf][b*5+q]  x rows, pad-5 (20KB)
    __shared__ int   sl[CAP];         // packed (e<<10)|t1 for this bin
    __shared__ int   scnt;

    int g   = blockIdx.x;
    int tid = threadIdx.x;

    // ---- phase 1: shared scan of dense pk, compact own edges ----
    if (tid == 0) scnt = 0;
    __syncthreads();
    const int4* pk4 = (const int4*)pk;
    for (int c = tid; c < EG / 4; c += 256) {      // 16 coalesced L2 iterations
        int4 w = pk4[c];
        int e0 = c << 2;
        if ((w.x >> 10) == g) { int p = atomicAdd(&scnt, 1); if (p < CAP) sl[p] = ((e0    ) << 10) | (w.x & 1023); }
        if ((w.y >> 10) == g) { int p = atomicAdd(&scnt, 1); if (p < CAP) sl[p] = ((e0 + 1) << 10) | (w.y & 1023); }
        if ((w.z >> 10) == g) { int p = atomicAdd(&scnt, 1); if (p < CAP) sl[p] = ((e0 + 2) << 10) | (w.z & 1023); }
        if ((w.w >> 10) == g) { int p = atomicAdd(&scnt, 1); if (p < CAP) sl[p] = ((e0 + 3) << 10) | (w.w & 1023); }
    }
    __syncthreads();
    int n = scnt; n = n < CAP ? n : CAP;

    // ---- phase 2: per-wave barrier-free depth-2 pipeline ----
    int wave = tid >> 6;
    int lane = tid & 63;
    int jg   = lane & 3;              // col group (4 cols)
    int cb2  = lane >> 2;             // batch 0..15 (acc0: cb2, acc1: cb2+16)

    // wave's edges: global list indices wave + 4k, k = 0..myn-1
    int myn = (n > wave) ? (((n - 1 - wave) >> 2) + 1) : 0;

    f32x4 acc0 = {0.f,0.f,0.f,0.f}, acc1 = {0.f,0.f,0.f,0.f};
    // two statically-named staging sets (edge k -> set k&1)
    f32x4 mA, lA, gA, x0A, x1A;
    f32x4 mB, lB, gB, x0B, x1B;

    auto issueA = [&](int k) {
        int pkv = sl[wave + (k << 2)];
        int e   = pkv >> 10, t1 = pkv & 1023;
        long wq = ((long)e << 6) + lane;
        mA = ((const f32x4*)wm)[wq];
        lA = ((const f32x4*)wlv)[wq];
        gA = ((const f32x4*)ew)[wq];
        const f32x4* x4 = (const f32x4*)x;
        int c0 = lane, c1 = lane + 64;
        x0A = x4[(long)(c0 >> 2) * (SIZE/4) + (t1 << 2) + (c0 & 3)];
        x1A = x4[(long)(c1 >> 2) * (SIZE/4) + (t1 << 2) + (c1 & 3)];
    };
    auto issueB = [&](int k) {
        int pkv = sl[wave + (k << 2)];
        int e   = pkv >> 10, t1 = pkv & 1023;
        long wq = ((long)e << 6) + lane;
        mB = ((const f32x4*)wm)[wq];
        lB = ((const f32x4*)wlv)[wq];
        gB = ((const f32x4*)ew)[wq];
        const f32x4* x4 = (const f32x4*)x;
        int c0 = lane, c1 = lane + 64;
        x0B = x4[(long)(c0 >> 2) * (SIZE/4) + (t1 << 2) + (c0 & 3)];
        x1B = x4[(long)(c1 >> 2) * (SIZE/4) + (t1 << 2) + (c1 & 3)];
    };
    auto writebA = [&](int buf) {           // reg-dep waitcnt lands here (counted)
        f32x4 v;
        v.x = gA.x * __expf(lA.x) + mA.x;
        v.y = gA.y * __expf(lA.y) + mA.y;
        v.z = gA.z * __expf(lA.z) + mA.z;
        v.w = gA.w * __expf(lA.w) + mA.w;
        vt[wave][buf][lane] = v;
        int c0 = lane, c1 = lane + 64;
        xs[wave][buf][(c0 >> 2) * 5 + (c0 & 3)] = x0A;
        xs[wave][buf][(c1 >> 2) * 5 + (c1 & 3)] = x1A;
    };
    auto writebB = [&](int buf) {
        f32x4 v;
        v.x = gB.x * __expf(lB.x) + mB.x;
        v.y = gB.y * __expf(lB.y) + mB.y;
        v.z = gB.z * __expf(lB.z) + mB.z;
        v.w = gB.w * __expf(lB.w) + mB.w;
        vt[wave][buf][lane] = v;
        int c0 = lane, c1 = lane + 64;
        xs[wave][buf][(c0 >> 2) * 5 + (c0 & 3)] = x0B;
        xs[wave][buf][(c1 >> 2) * 5 + (c1 & 3)] = x1B;
    };
    auto compute = [&](int buf) {           // own-wave LDS only: lgkmcnt orders
        #pragma unroll
        for (int q = 0; q < 4; ++q) {       // quad-structured: 8 f32x4 live max
            f32x4 xa = xs[wave][buf][ cb2       * 5 + q];
            f32x4 xb = xs[wave][buf][(cb2 + 16) * 5 + q];
            f32x4 w0 = vt[wave][buf][(q << 4) + 0  + jg];
            f32x4 w1 = vt[wave][buf][(q << 4) + 4  + jg];
            f32x4 w2 = vt[wave][buf][(q << 4) + 8  + jg];
            f32x4 w3 = vt[wave][buf][(q << 4) + 12 + jg];
            acc0 += w0 * xa.x; acc0 += w1 * xa.y;
            acc0 += w2 * xa.z; acc0 += w3 * xa.w;
            acc1 += w0 * xb.x; acc1 += w1 * xb.y;
            acc1 += w2 * xb.z; acc1 += w3 * xb.w;
        }
    };

    // prologue: edge k uses set k&1 and buf k&1
    if (myn > 0) issueA(0);
    if (myn > 1) issueB(1);
    if (myn > 0) writebA(0);
    // main loop: NO barriers; depth-2 in flight
    for (int k = 0; k < myn; ++k) {
        compute(k & 1);
        if (k + 2 < myn) {                  // refill the set just drained to LDS
            if ((k & 1) == 0) issueA(k + 2); else issueB(k + 2);
        }
        if (k + 1 < myn) {                  // write next edge's tiles
            if ((k & 1) == 0) writebB((k + 1) & 1); else writebA((k + 1) & 1);
        }
    }

    // ---- epilogue: cross-wave reduce + fused bias + exclusive store ----
    __syncthreads();                        // all waves done with xs (overlay)
    f32x4* sred = &xs[0][0][0];             // 512 f32x4 overlay
    sred[(wave << 7) + (lane << 1) + 0] = acc0;
    sred[(wave << 7) + (lane << 1) + 1] = acc1;
    __syncthreads();
    if (tid < 128) {
        int cb  = tid >> 2;                // batch 0..31
        int jgf = tid & 3;
        int h   = cb >> 4;                 // which accumulator half
        int sl_ = ((cb & 15) << 2) + jgf;  // lane in wave
        f32x4 s = sred[(0 << 7) + (sl_ << 1) + h]
                + sred[(1 << 7) + (sl_ << 1) + h]
                + sred[(2 << 7) + (sl_ << 1) + h]
                + sred[(3 << 7) + (sl_ << 1) + h];
        int r0 = (g << 4) + (jgf << 2);    // 16B-aligned
        f32x4 b4 = *(const f32x4*)&bm[r0];
        f32x4 v4 = *(const f32x4*)&blv[r0];
        f32x4 e4 = *(const f32x4*)&eb[r0];
        f32x4 o;
        o.x = s.x + (e4.x * __expf(v4.x) + b4.x);
        o.y = s.y + (e4.y * __expf(v4.y) + b4.y);
        o.z = s.z + (e4.z * __expf(v4.z) + b4.z);
        o.w = s.w + (e4.w * __expf(v4.w) + b4.w);
        *(f32x4*)&out[(long)cb * SIZE + r0] = o;
    }
    if (g == 0 && tid == 0) out[(long)BB * SIZE] = 0.0f;   // kl scalar
}

extern "C" void kernel_launch(void* const* d_in, const int* in_sizes, int n_in,
                              void* d_out, int out_size, void* d_ws, size_t ws_size,
                              hipStream_t stream) {
    const float* x   = (const float*)d_in[0];
    const float* wm  = (const float*)d_in[1];
    const float* wlv = (const float*)d_in[2];
    const float* bm  = (const float*)d_in[3];
    const float* blv = (const float*)d_in[4];
    const float* ew  = (const float*)d_in[5];
    const float* eb  = (const float*)d_in[6];
    const int* rows  = (const int*)d_in[7];
    const int* cols  = (const int*)d_in[8];
    float* out = (float*)d_out;

    int* pk = (int*)d_ws;                 // 16000 ints = 64KB dense edge headers

    pack_kernel<<<(EG + 255) / 256, 256, 0, stream>>>(rows, cols, pk);
    spmm_kernel<<<NG, 256, 0, stream>>>(wm, wlv, ew, x, bm, blv, eb, pk, out);
}

// Round 16
// 132.736 us; speedup vs baseline: 1.6191x; 1.6191x over previous
//
#include <hip/hip_runtime.h>

#define EG   16000   // graph edges
#define NG   1000    // graph_size (block rows/cols)
#define BB   32      // batch
#define SIZE 16000   // feature length (NG*16)
#define CAP  64      // per-bin capacity (Poisson(16): P(>64) ~ 1e-18)

typedef float f32x4 __attribute__((ext_vector_type(4)));

// ---- kernel 1: gather strided edge headers into dense pk[e]=(t0<<10)|t1 ----
// Writes every entry each launch: ws poison is never read. No memset needed.
__global__ __launch_bounds__(256) void pack_kernel(
    const int* __restrict__ rows, const int* __restrict__ cols,
    int* __restrict__ pk)
{
    int e = blockIdx.x * 256 + threadIdx.x;
    if (e < EG) {
        int t0 = rows[(long)e << 8] >> 4;   // rows[e*256] = t0*16
        int t1 = cols[(long)e << 8] >> 4;   // cols[e*256] = t1*16
        pk[e] = (t0 << 10) | t1;            // 20 bits
    }
}

// ---- kernel 2: r10 lockstep spmm MINUS the main-loop barriers ----
// Single-variable experiment vs r10 (133.0us): the 4 waves share NOTHING in
// the main loop (per-wave LDS slots; own-wave ds_write->ds_read ordered by
// compiler lgkmcnt -- mechanism proven correct in r12). The per-iteration
// __syncthreads was pure coupling: all waves drained vmcnt(0) in phase and
// restarted together. Deleting it lets waves drift and de-phase their HBM
// bursts; 16 waves/CU then actually cover each other's latency.
// Everything else is r10 verbatim: shared scan (1 barrier), lockstep edge
// assignment wave+4k (same summation order -> same absmax), depth-1 staging
// with 5 live f32x4 (r12/r15 lesson: wider staging sets spill to scratch,
// 2-6x regression), quad-structured compute (no register arrays).
// NOTE (r8/r9): no in-kernel grid barriers. NOTE (r3): stores line-clustered,
// wave-private.
__global__ __launch_bounds__(256, 4) void spmm_kernel(
    const float* __restrict__ wm, const float* __restrict__ wlv,
    const float* __restrict__ ew, const float* __restrict__ x,
    const float* __restrict__ bm, const float* __restrict__ blv,
    const float* __restrict__ eb, const int* __restrict__ pk,
    float* __restrict__ out)
{
    __shared__ f32x4 vt[2][4][64];    // [buf][wave][i*4+jg] sampled weights (8KB)
    __shared__ f32x4 xs[2][4][160];   // [buf][wave][b*5+q]  x rows, pad-5 (20KB)
    __shared__ int   sl[CAP];         // packed (e<<10)|t1 for this bin
    __shared__ int   scnt;

    int g   = blockIdx.x;
    int tid = threadIdx.x;

    // ---- phase 1: shared scan of dense pk, compact own edges ----
    if (tid == 0) scnt = 0;
    __syncthreads();
    const int4* pk4 = (const int4*)pk;
    for (int c = tid; c < EG / 4; c += 256) {      // 16 coalesced L2 iterations
        int4 w = pk4[c];
        int e0 = c << 2;
        if ((w.x >> 10) == g) { int p = atomicAdd(&scnt, 1); if (p < CAP) sl[p] = ((e0    ) << 10) | (w.x & 1023); }
        if ((w.y >> 10) == g) { int p = atomicAdd(&scnt, 1); if (p < CAP) sl[p] = ((e0 + 1) << 10) | (w.y & 1023); }
        if ((w.z >> 10) == g) { int p = atomicAdd(&scnt, 1); if (p < CAP) sl[p] = ((e0 + 2) << 10) | (w.z & 1023); }
        if ((w.w >> 10) == g) { int p = atomicAdd(&scnt, 1); if (p < CAP) sl[p] = ((e0 + 3) << 10) | (w.w & 1023); }
    }
    __syncthreads();
    int n = scnt; n = n < CAP ? n : CAP;

    // ---- phase 2: lockstep-assigned, barrier-free main loop ----
    int wave = tid >> 6;              // edge slot 0..3
    int lane = tid & 63;
    int jg   = lane & 3;              // col group (4 cols)
    int cb2  = lane >> 2;             // batch 0..15 (acc0: cb2, acc1: cb2+16)

    f32x4 acc0 = {0.f,0.f,0.f,0.f}, acc1 = {0.f,0.f,0.f,0.f};
    f32x4 m4, l4, g4, xv0, xv1;       // depth-1 staging: 5 live f32x4 (no spill)
    int iters = (n + 3) >> 2;
    bool vcur = false, vnxt = false;

    auto issue = [&](int idx) -> bool {     // global loads only (no LDS writes)
        bool val = idx < n;
        if (val) {                          // wave-uniform branch
            int pkv = sl[idx];
            int e   = pkv >> 10;
            int t1  = pkv & 1023;
            long wq = ((long)e << 6) + lane;
            m4 = ((const f32x4*)wm)[wq];    // 3 x b128, coalesced 1KB/wave
            l4 = ((const f32x4*)wlv)[wq];
            g4 = ((const f32x4*)ew)[wq];
            const f32x4* x4 = (const f32x4*)x;
            int c0 = lane, c1 = lane + 64;  // chunk = (b = c>>2, q = c&3)
            xv0 = x4[(long)(c0 >> 2) * (SIZE/4) + (t1 << 2) + (c0 & 3)];
            xv1 = x4[(long)(c1 >> 2) * (SIZE/4) + (t1 << 2) + (c1 & 3)];
        }
        return val;
    };
    auto writeb = [&](int buf, bool val) {  // reg-dep vmcnt wait lands here
        if (val) {
            f32x4 v;
            v.x = g4.x * __expf(l4.x) + m4.x;
            v.y = g4.y * __expf(l4.y) + m4.y;
            v.z = g4.z * __expf(l4.z) + m4.z;
            v.w = g4.w * __expf(l4.w) + m4.w;
            vt[buf][wave][lane] = v;        // chunk lane = (i=lane>>2, jg=lane&3)
            int c0 = lane, c1 = lane + 64;
            xs[buf][wave][(c0 >> 2) * 5 + (c0 & 3)] = xv0;
            xs[buf][wave][(c1 >> 2) * 5 + (c1 & 3)] = xv1;
        }
    };
    auto compute = [&](int buf, bool val) { // own-wave LDS only: lgkmcnt orders
        if (!val) return;                   // wave-uniform
        #pragma unroll
        for (int q = 0; q < 4; ++q) {       // quad-structured: 8 f32x4 live max
            f32x4 xa = xs[buf][wave][ cb2       * 5 + q];
            f32x4 xb = xs[buf][wave][(cb2 + 16) * 5 + q];
            f32x4 w0 = vt[buf][wave][(q << 4) + 0  + jg];
            f32x4 w1 = vt[buf][wave][(q << 4) + 4  + jg];
            f32x4 w2 = vt[buf][wave][(q << 4) + 8  + jg];
            f32x4 w3 = vt[buf][wave][(q << 4) + 12 + jg];
            acc0 += w0 * xa.x; acc0 += w1 * xa.y;
            acc0 += w2 * xa.z; acc0 += w3 * xa.w;
            acc1 += w0 * xb.x; acc1 += w1 * xb.y;
            acc1 += w2 * xb.z; acc1 += w3 * xb.w;
        }
    };

    // prologue (no barrier: all LDS traffic is wave-private from here on)
    vcur = issue(wave);
    writeb(0, vcur);
    // main loop: NO __syncthreads -- waves free-run their lockstep-assigned edges
    for (int it = 0; it < iters; ++it) {
        bool more = (it + 1 < iters);
        if (more) vnxt = issue(((it + 1) << 2) + wave);  // globals in flight
        compute(it & 1, vcur);                            // LDS+VALU overlap
        if (more) writeb((it + 1) & 1, vnxt);
        vcur = vnxt;
    }

    // ---- epilogue: cross-wave reduce + fused bias + exclusive store ----
    __syncthreads();                        // all waves done with xs (overlay)
    f32x4* sred = &xs[0][0][0];             // overlay: xs dead after barrier
    sred[(wave << 7) + (lane << 1) + 0] = acc0;
    sred[(wave << 7) + (lane << 1) + 1] = acc1;
    __syncthreads();
    if (tid < 128) {
        int cb  = tid >> 2;                // batch 0..31
        int jgf = tid & 3;
        int h   = cb >> 4;                 // which accumulator half
        int sl_ = ((cb & 15) << 2) + jgf;  // lane in wave
        f32x4 s = sred[(0 << 7) + (sl_ << 1) + h]
                + sred[(1 << 7) + (sl_ << 1) + h]
                + sred[(2 << 7) + (sl_ << 1) + h]
                + sred[(3 << 7) + (sl_ << 1) + h];
        int r0 = (g << 4) + (jgf << 2);    // 16B-aligned
        f32x4 b4 = *(const f32x4*)&bm[r0];
        f32x4 v4 = *(const f32x4*)&blv[r0];
        f32x4 e4 = *(const f32x4*)&eb[r0];
        f32x4 o;
        o.x = s.x + (e4.x * __expf(v4.x) + b4.x);
        o.y = s.y + (e4.y * __expf(v4.y) + b4.y);
        o.z = s.z + (e4.z * __expf(v4.z) + b4.z);
        o.w = s.w + (e4.w * __expf(v4.w) + b4.w);
        *(f32x4*)&out[(long)cb * SIZE + r0] = o;
    }
    if (g == 0 && tid == 0) out[(long)BB * SIZE] = 0.0f;   // kl scalar
}

extern "C" void kernel_launch(void* const* d_in, const int* in_sizes, int n_in,
                              void* d_out, int out_size, void* d_ws, size_t ws_size,
                              hipStream_t stream) {
    const float* x   = (const float*)d_in[0];
    const float* wm  = (const float*)d_in[1];
    const float* wlv = (const float*)d_in[2];
    const float* bm  = (const float*)d_in[3];
    const float* blv = (const float*)d_in[4];
    const float* ew  = (const float*)d_in[5];
    const float* eb  = (const float*)d_in[6];
    const int* rows  = (const int*)d_in[7];
    const int* cols  = (const int*)d_in[8];
    float* out = (float*)d_out;

    int* pk = (int*)d_ws;                 // 16000 ints = 64KB dense edge headers

    pack_kernel<<<(EG + 255) / 256, 256, 0, stream>>>(rows, cols, pk);
    spmm_kernel<<<NG, 256, 0, stream>>>(wm, wlv, ew, x, bm, blv, eb, pk, out);
}